// Round 1
// baseline (105.754 us; speedup 1.0000x reference)
//
#include <hip/hip_runtime.h>
#include <hip/hip_bf16.h>

// out[n][d] = x[n][d] + params[d]; N=16384, D=4096, fp32.
// Memory-bound broadcast add. float4 vectorized, grid-stride.
// D/4 = 1024 (pow2) -> params float4 index = i & 1023 (no idiv).

__global__ __launch_bounds__(256) void TranslationNet_90658169684623_kernel(
    const float4* __restrict__ x,
    const float4* __restrict__ p,
    float4* __restrict__ out,
    long long n4)
{
    long long i = (long long)blockIdx.x * blockDim.x + threadIdx.x;
    const long long stride = (long long)gridDim.x * blockDim.x;
    for (; i < n4; i += stride) {
        float4 xv = x[i];
        float4 pv = p[i & 1023];   // (i % (D/4)), D/4 = 1024
        float4 o;
        o.x = xv.x + pv.x;
        o.y = xv.y + pv.y;
        o.z = xv.z + pv.z;
        o.w = xv.w + pv.w;
        out[i] = o;
    }
}

extern "C" void kernel_launch(void* const* d_in, const int* in_sizes, int n_in,
                              void* d_out, int out_size, void* d_ws, size_t ws_size,
                              hipStream_t stream) {
    const float4* x = (const float4*)d_in[0];       // (N, D) fp32
    const float4* p = (const float4*)d_in[1];       // (D,)  fp32
    float4* out = (float4*)d_out;                   // (N, D) fp32

    const long long n4 = (long long)out_size / 4;   // 16M float4
    const int block = 256;
    const int grid = 2048;                          // 256 CU x 8, grid-stride

    TranslationNet_90658169684623_kernel<<<grid, block, 0, stream>>>(x, p, out, n4);
}

// Round 3
// 92.650 us; speedup vs baseline: 1.1414x; 1.1414x over previous
//
#include <hip/hip_runtime.h>
#include <hip/hip_bf16.h>

// out[n][d] = x[n][d] + params[d]; N=16384, D=4096, fp32.
// Memory-bound broadcast add, traffic floor 512 MiB (read x + write out).
// Round 3: same as round 2 but with a native clang ext_vector float4
// (HIP's float4 is a class type that __builtin_nontemporal_store rejects).

typedef float f4 __attribute__((ext_vector_type(4)));

__global__ __launch_bounds__(256) void TranslationNet_90658169684623_kernel(
    const f4* __restrict__ x,
    const f4* __restrict__ p,
    f4* __restrict__ out,
    long long n4)
{
    const long long tid    = (long long)blockIdx.x * blockDim.x + threadIdx.x;
    const long long stride = (long long)gridDim.x * blockDim.x;   // 2^19, multiple of 1024

    // Column (float4 units) = tid & 1023, invariant across grid-stride
    // iterations because stride % 1024 == 0. Load bias once.
    const f4 pv = p[tid & 1023];

    long long i = tid;
    const long long step4 = 4 * stride;
    // Main unrolled loop: 4 independent loads in flight before any store.
    for (; i + 3 * stride < n4; i += step4) {
        f4 a = x[i];
        f4 b = x[i + stride];
        f4 c = x[i + 2 * stride];
        f4 d = x[i + 3 * stride];
        a += pv;
        b += pv;
        c += pv;
        d += pv;
        __builtin_nontemporal_store(a, &out[i]);
        __builtin_nontemporal_store(b, &out[i + stride]);
        __builtin_nontemporal_store(c, &out[i + 2 * stride]);
        __builtin_nontemporal_store(d, &out[i + 3 * stride]);
    }
    // Tail (never taken for this shape/grid, but safe).
    for (; i < n4; i += stride) {
        f4 a = x[i];
        a += pv;
        __builtin_nontemporal_store(a, &out[i]);
    }
}

extern "C" void kernel_launch(void* const* d_in, const int* in_sizes, int n_in,
                              void* d_out, int out_size, void* d_ws, size_t ws_size,
                              hipStream_t stream) {
    const f4* x = (const f4*)d_in[0];       // (N, D) fp32
    const f4* p = (const f4*)d_in[1];       // (D,)  fp32
    f4* out = (f4*)d_out;                   // (N, D) fp32

    const long long n4 = (long long)out_size / 4;   // 16M float4
    const int block = 256;
    const int grid = 2048;                          // 2^19 threads total

    TranslationNet_90658169684623_kernel<<<grid, block, 0, stream>>>(x, p, out, n4);
}

// Round 4
// 91.465 us; speedup vs baseline: 1.1562x; 1.0130x over previous
//
#include <hip/hip_runtime.h>
#include <hip/hip_bf16.h>

// out[n][d] = x[n][d] + params[d]; N=16384, D=4096, fp32.
// Memory-bound broadcast add, traffic floor 512 MiB (read x + write out).
// Round 4: unroll 8 (8 independent loads in flight per wave) to attack the
// latency/MLP gap — at 92.6us we were at 4.3 TB/s HBM demand (L3 serves
// half of x), well under the 6.3 TB/s ceiling, so not BW-bound yet.

typedef float f4 __attribute__((ext_vector_type(4)));

__global__ __launch_bounds__(256) void TranslationNet_90658169684623_kernel(
    const f4* __restrict__ x,
    const f4* __restrict__ p,
    f4* __restrict__ out,
    long long n4)
{
    const long long tid    = (long long)blockIdx.x * blockDim.x + threadIdx.x;
    const long long stride = (long long)gridDim.x * blockDim.x;   // 2^19, multiple of 1024

    // Column (float4 units) = tid & 1023, invariant across grid-stride
    // iterations because stride % 1024 == 0. Load bias once.
    const f4 pv = p[tid & 1023];

    long long i = tid;
    const long long step8 = 8 * stride;
    // Main unrolled loop: 8 independent loads in flight before any store.
    for (; i + 7 * stride < n4; i += step8) {
        f4 a0 = x[i];
        f4 a1 = x[i + stride];
        f4 a2 = x[i + 2 * stride];
        f4 a3 = x[i + 3 * stride];
        f4 a4 = x[i + 4 * stride];
        f4 a5 = x[i + 5 * stride];
        f4 a6 = x[i + 6 * stride];
        f4 a7 = x[i + 7 * stride];
        a0 += pv; a1 += pv; a2 += pv; a3 += pv;
        a4 += pv; a5 += pv; a6 += pv; a7 += pv;
        __builtin_nontemporal_store(a0, &out[i]);
        __builtin_nontemporal_store(a1, &out[i + stride]);
        __builtin_nontemporal_store(a2, &out[i + 2 * stride]);
        __builtin_nontemporal_store(a3, &out[i + 3 * stride]);
        __builtin_nontemporal_store(a4, &out[i + 4 * stride]);
        __builtin_nontemporal_store(a5, &out[i + 5 * stride]);
        __builtin_nontemporal_store(a6, &out[i + 6 * stride]);
        __builtin_nontemporal_store(a7, &out[i + 7 * stride]);
    }
    // Tail (never taken for this shape/grid, but safe).
    for (; i < n4; i += stride) {
        f4 a = x[i];
        a += pv;
        __builtin_nontemporal_store(a, &out[i]);
    }
}

extern "C" void kernel_launch(void* const* d_in, const int* in_sizes, int n_in,
                              void* d_out, int out_size, void* d_ws, size_t ws_size,
                              hipStream_t stream) {
    const f4* x = (const f4*)d_in[0];       // (N, D) fp32
    const f4* p = (const f4*)d_in[1];       // (D,)  fp32
    f4* out = (f4*)d_out;                   // (N, D) fp32

    const long long n4 = (long long)out_size / 4;   // 16M float4
    const int block = 256;
    const int grid = 2048;                          // 2^19 threads total

    TranslationNet_90658169684623_kernel<<<grid, block, 0, stream>>>(x, p, out, n4);
}

// Round 5
// 85.080 us; speedup vs baseline: 1.2430x; 1.0751x over previous
//
#include <hip/hip_runtime.h>
#include <hip/hip_bf16.h>

// out[n][d] = x[n][d] + params[d]; N=16384, D=4096, fp32.
// Memory-bound broadcast add, traffic floor 512 MiB logical.
// Round 5: single-pass kernel — grid 8192 x 256, 8 float4/thread, NO
// grid-stride loop. Removes the loop back-edge's store->VGPR-reuse
// s_waitcnt serialization (R4's 8x MLP unroll was neutral, so the gap
// wasn't in-loop MLP). Stride 2^21 is a multiple of D/4=1024 -> params
// float4 still fixed per thread.

typedef float f4 __attribute__((ext_vector_type(4)));

__global__ __launch_bounds__(256) void TranslationNet_90658169684623_kernel(
    const f4* __restrict__ x,
    const f4* __restrict__ p,
    f4* __restrict__ out,
    long long n4)
{
    const long long tid    = (long long)blockIdx.x * blockDim.x + threadIdx.x;
    const long long stride = (long long)gridDim.x * blockDim.x;   // 2^21, multiple of 1024

    const f4 pv = p[tid & 1023];

    // Exact cover: n4 = 16M = 8 * stride. Guard anyway (cheap, uniform).
    if (tid + 7 * stride < n4) {
        f4 a0 = x[tid];
        f4 a1 = x[tid + stride];
        f4 a2 = x[tid + 2 * stride];
        f4 a3 = x[tid + 3 * stride];
        f4 a4 = x[tid + 4 * stride];
        f4 a5 = x[tid + 5 * stride];
        f4 a6 = x[tid + 6 * stride];
        f4 a7 = x[tid + 7 * stride];
        a0 += pv; a1 += pv; a2 += pv; a3 += pv;
        a4 += pv; a5 += pv; a6 += pv; a7 += pv;
        __builtin_nontemporal_store(a0, &out[tid]);
        __builtin_nontemporal_store(a1, &out[tid + stride]);
        __builtin_nontemporal_store(a2, &out[tid + 2 * stride]);
        __builtin_nontemporal_store(a3, &out[tid + 3 * stride]);
        __builtin_nontemporal_store(a4, &out[tid + 4 * stride]);
        __builtin_nontemporal_store(a5, &out[tid + 5 * stride]);
        __builtin_nontemporal_store(a6, &out[tid + 6 * stride]);
        __builtin_nontemporal_store(a7, &out[tid + 7 * stride]);
    } else {
        // Safety tail (not taken for this shape/grid).
        for (long long i = tid; i < n4; i += stride) {
            f4 a = x[i];
            a += pv;
            __builtin_nontemporal_store(a, &out[i]);
        }
    }
}

extern "C" void kernel_launch(void* const* d_in, const int* in_sizes, int n_in,
                              void* d_out, int out_size, void* d_ws, size_t ws_size,
                              hipStream_t stream) {
    const f4* x = (const f4*)d_in[0];       // (N, D) fp32
    const f4* p = (const f4*)d_in[1];       // (D,)  fp32
    f4* out = (f4*)d_out;                   // (N, D) fp32

    const long long n4 = (long long)out_size / 4;   // 16M float4
    const int block = 256;
    const int grid = 8192;                          // 2^21 threads, 8 f4/thread, single pass

    TranslationNet_90658169684623_kernel<<<grid, block, 0, stream>>>(x, p, out, n4);
}